// Round 2
// baseline (1035.635 us; speedup 1.0000x reference)
//
#include <hip/hip_runtime.h>
#include <math.h>

#define Bq 8
#define Hq 256
#define Wq 256
#define Cq 64
#define HID 8
#define PI_F 3.14159265358979323846f

__device__ __forceinline__ float wred(float v) {
    v += __shfl_xor(v, 32, 64);
    v += __shfl_xor(v, 16, 64);
    v += __shfl_xor(v, 8, 64);
    v += __shfl_xor(v, 4, 64);
    v += __shfl_xor(v, 2, 64);
    v += __shfl_xor(v, 1, 64);
    return v;
}

// Bilinear sample of img (one batch image, [H,W,C]) at (cy, cx), channel = lane.
// Faithful to reference: weights computed from CLIPPED integer corner coords.
__device__ __forceinline__ float bilin(const float* __restrict__ img,
                                       float cy, float cx, int lane) {
    float fy0 = floorf(cy);
    float fx0 = floorf(cx);
    int y0 = (int)fy0;
    int x0 = (int)fx0;
    int y0i = min(max(y0, 0), Hq - 1);
    int x0i = min(max(x0, 0), Wq - 1);
    int y1i = min(max(y0 + 1, 0), Hq - 1);
    int x1i = min(max(x0 + 1, 0), Wq - 1);
    float y0f = (float)y0i, x0f = (float)x0i;
    float y1f = (float)y1i, x1f = (float)x1i;
    float wy0 = y1f - cy;   // pairs with y0i rows
    float wy1 = cy - y0f;   // pairs with y1i rows
    float wx0 = x1f - cx;   // pairs with x0i cols
    float wx1 = cx - x0f;   // pairs with x1i cols
    float Ia = img[((size_t)(y0i * Wq) + x0i) * Cq + lane];
    float Ib = img[((size_t)(y1i * Wq) + x0i) * Cq + lane];
    float Ic = img[((size_t)(y0i * Wq) + x1i) * Cq + lane];
    float Id = img[((size_t)(y1i * Wq) + x1i) * Cq + lane];
    return (wx0 * wy0) * Ia + (wx0 * wy1) * Ib + (wx1 * wy0) * Ic + (wx1 * wy1) * Id;
}

__global__ __launch_bounds__(256) void oca_kernel(
    const float* __restrict__ x,
    const float* __restrict__ w3, const float* __restrict__ b3,
    const float* __restrict__ w1, const float* __restrict__ b1,
    const float* __restrict__ wr, const float* __restrict__ br,
    const float* __restrict__ we, const float* __restrict__ be,
    float* __restrict__ out) {
    const int wid  = blockIdx.x * (blockDim.x >> 6) + (threadIdx.x >> 6);
    const int lane = threadIdx.x & 63;
    const int b  = wid >> 16;          // H*W = 65536
    const int yq = (wid >> 8) & 255;
    const int xq = wid & 255;
    const float* img = x + (size_t)b * (Hq * (size_t)Wq * Cq);

    // ---- h = relu(conv3x3(x, w3) + b3), lane-parallel over input channel ----
    float hacc[HID];
#pragma unroll
    for (int j = 0; j < HID; ++j) hacc[j] = 0.f;
#pragma unroll
    for (int dy = -1; dy <= 1; ++dy) {
        int yy = yq + dy;
        if ((unsigned)yy >= (unsigned)Hq) continue;
#pragma unroll
        for (int dx = -1; dx <= 1; ++dx) {
            int xx = xq + dx;
            if ((unsigned)xx >= (unsigned)Wq) continue;
            float xv = img[((size_t)(yy * Wq) + xx) * Cq + lane];
            const float* wp = w3 + (size_t)(((dy + 1) * 3 + (dx + 1)) * Cq + lane) * HID;
            float4 w0 = *(const float4*)(wp);
            float4 w1v = *(const float4*)(wp + 4);
            hacc[0] = fmaf(xv, w0.x, hacc[0]);
            hacc[1] = fmaf(xv, w0.y, hacc[1]);
            hacc[2] = fmaf(xv, w0.z, hacc[2]);
            hacc[3] = fmaf(xv, w0.w, hacc[3]);
            hacc[4] = fmaf(xv, w1v.x, hacc[4]);
            hacc[5] = fmaf(xv, w1v.y, hacc[5]);
            hacc[6] = fmaf(xv, w1v.z, hacc[6]);
            hacc[7] = fmaf(xv, w1v.w, hacc[7]);
        }
    }
    float h[HID];
#pragma unroll
    for (int j = 0; j < HID; ++j) {
        float s = wred(hacc[j]) + b3[j];
        h[j] = fmaxf(s, 0.f);
    }

    // ---- theta = pi * sigmoid(conv1x1(h, w1) + b1) ----
    float z = b1[0];
#pragma unroll
    for (int j = 0; j < HID; ++j) z = fmaf(h[j], w1[j], z);
    float theta = PI_F / (1.f + expf(-z));
    float ct = cosf(theta);
    float st = sinf(theta);

    // ---- oriented pooling: tangential (vx=cos, vy=sin), normal (vx=-sin, vy=cos) ----
    const float fy = (float)yq, fx = (float)xq;
    float acc_t = 0.f, acc_n = 0.f;
#pragma unroll
    for (int t = -4; t <= 4; ++t) {
        float tf = (float)t;
        acc_t += bilin(img, fy + tf * st, fx + tf * ct, lane);
        acc_n += bilin(img, fy + tf * ct, fx - tf * st, lane);
    }
    float tanv = acc_t / 9.0f;
    float norv = acc_n / 9.0f;

    // ---- r = relu(conv1x1(context, wr) + br), context = [tan(64), nor(64)] ----
    const float* wrp0 = wr + (size_t)lane * HID;
    const float* wrp1 = wr + (size_t)(64 + lane) * HID;
    float4 a0 = *(const float4*)(wrp0);
    float4 a1 = *(const float4*)(wrp0 + 4);
    float4 c0 = *(const float4*)(wrp1);
    float4 c1 = *(const float4*)(wrp1 + 4);
    float p[HID];
    p[0] = fmaf(tanv, a0.x, norv * c0.x);
    p[1] = fmaf(tanv, a0.y, norv * c0.y);
    p[2] = fmaf(tanv, a0.z, norv * c0.z);
    p[3] = fmaf(tanv, a0.w, norv * c0.w);
    p[4] = fmaf(tanv, a1.x, norv * c1.x);
    p[5] = fmaf(tanv, a1.y, norv * c1.y);
    p[6] = fmaf(tanv, a1.z, norv * c1.z);
    p[7] = fmaf(tanv, a1.w, norv * c1.w);
    float r[HID];
#pragma unroll
    for (int j = 0; j < HID; ++j) {
        float s = wred(p[j]) + br[j];
        r[j] = fmaxf(s, 0.f);
    }

    // ---- w = sigmoid(conv1x1(r, we) + be); out = (w_tan + w_nor) * x ----
    float zt = be[lane];
    float zn = be[64 + lane];
#pragma unroll
    for (int j = 0; j < HID; ++j) {
        zt = fmaf(r[j], we[(size_t)j * 128 + lane], zt);
        zn = fmaf(r[j], we[(size_t)j * 128 + 64 + lane], zn);
    }
    float wt = 1.f / (1.f + expf(-zt));
    float wn = 1.f / (1.f + expf(-zn));
    float xc = img[((size_t)(yq * Wq) + xq) * Cq + lane];
    out[(size_t)wid * Cq + lane] = (wt + wn) * xc;
}

extern "C" void kernel_launch(void* const* d_in, const int* in_sizes, int n_in,
                              void* d_out, int out_size, void* d_ws, size_t ws_size,
                              hipStream_t stream) {
    const float* x  = (const float*)d_in[0];
    const float* w3 = (const float*)d_in[1];
    const float* b3 = (const float*)d_in[2];
    const float* w1 = (const float*)d_in[3];
    const float* b1 = (const float*)d_in[4];
    const float* wr = (const float*)d_in[5];
    const float* br = (const float*)d_in[6];
    const float* we = (const float*)d_in[7];
    const float* be = (const float*)d_in[8];
    float* out = (float*)d_out;

    const int total_waves = Bq * Hq * Wq;           // one wave per pixel
    const int waves_per_block = 4;                  // 256 threads
    dim3 grid(total_waves / waves_per_block), block(256);
    oca_kernel<<<grid, block, 0, stream>>>(x, w3, b3, w1, b1, wr, br, we, be, out);
}

// Round 3
// 913.767 us; speedup vs baseline: 1.1334x; 1.1334x over previous
//
#include <hip/hip_runtime.h>
#include <math.h>

#define Bq 8
#define Hq 256
#define Wq 256
#define Cq 64
#define HID 8
#define PI_F 3.14159265358979323846f

// Fold 8 per-lane accumulators (each to be summed over all 64 lanes) into one
// value per lane: lane l returns the full-wave sum of v[l&7].
// Phase A (strides 4,2,1) folds the value dimension so j = lane&7;
// Phase B (strides 8,16,32) completes the cross-group sum.
__device__ __forceinline__ float fold8(float v0, float v1, float v2, float v3,
                                       float v4, float v5, float v6, float v7,
                                       int lane) {
    const bool b4 = (lane & 4) != 0;
    float k0 = b4 ? v4 : v0, g0 = b4 ? v0 : v4;
    float k1 = b4 ? v5 : v1, g1 = b4 ? v1 : v5;
    float k2 = b4 ? v6 : v2, g2 = b4 ? v2 : v6;
    float k3 = b4 ? v7 : v3, g3 = b4 ? v3 : v7;
    k0 += __shfl_xor(g0, 4, 64);
    k1 += __shfl_xor(g1, 4, 64);
    k2 += __shfl_xor(g2, 4, 64);
    k3 += __shfl_xor(g3, 4, 64);
    const bool b2 = (lane & 2) != 0;
    float m0 = b2 ? k2 : k0, n0 = b2 ? k0 : k2;
    float m1 = b2 ? k3 : k1, n1 = b2 ? k1 : k3;
    m0 += __shfl_xor(n0, 2, 64);
    m1 += __shfl_xor(n1, 2, 64);
    const bool b1_ = (lane & 1) != 0;
    float q = b1_ ? m1 : m0, r = b1_ ? m0 : m1;
    q += __shfl_xor(r, 1, 64);
    q += __shfl_xor(q, 8, 64);
    q += __shfl_xor(q, 16, 64);
    q += __shfl_xor(q, 32, 64);
    return q;
}

// Bilinear sample; cy,cx are wave-uniform. Integer corner work is pushed to
// the SALU via readfirstlane; loads become SGPR-base + lane*4.
// Weights use CLIPPED integer corner coords (faithful to reference).
__device__ __forceinline__ float bilin_s(const float* __restrict__ img,
                                         float cy, float cx, int lane) {
    float fy0 = floorf(cy);
    float fx0 = floorf(cx);
    int y0 = __builtin_amdgcn_readfirstlane((int)fy0);
    int x0 = __builtin_amdgcn_readfirstlane((int)fx0);
    int y0i = min(max(y0, 0), Hq - 1);
    int x0i = min(max(x0, 0), Wq - 1);
    int y1i = min(max(y0 + 1, 0), Hq - 1);
    int x1i = min(max(x0 + 1, 0), Wq - 1);
    float wy0 = (float)y1i - cy;
    float wy1 = cy - (float)y0i;
    float wx0 = (float)x1i - cx;
    float wx1 = cx - (float)x0i;
    const float* pa = img + (size_t)(((y0i << 8) + x0i) << 6);
    const float* pb = img + (size_t)(((y1i << 8) + x0i) << 6);
    const float* pc = img + (size_t)(((y0i << 8) + x1i) << 6);
    const float* pd = img + (size_t)(((y1i << 8) + x1i) << 6);
    float Ia = pa[lane], Ib = pb[lane], Ic = pc[lane], Id = pd[lane];
    return (wx0 * wy0) * Ia + (wx0 * wy1) * Ib + (wx1 * wy0) * Ic + (wx1 * wy1) * Id;
}

__global__ __launch_bounds__(256) void oca_kernel(
    const float* __restrict__ x,
    const float* __restrict__ w3, const float* __restrict__ b3,
    const float* __restrict__ w1, const float* __restrict__ b1,
    const float* __restrict__ wr, const float* __restrict__ br,
    const float* __restrict__ we, const float* __restrict__ be,
    float* __restrict__ out) {
    const int lane = threadIdx.x & 63;
    // wave-uniform pixel id, forced into SGPRs so all derived addressing is scalar
    const int wid = __builtin_amdgcn_readfirstlane(blockIdx.x * 4 + (threadIdx.x >> 6));
    const int b  = wid >> 16;
    const int yq = (wid >> 8) & 255;
    const int xq = wid & 255;
    const float* img = x + ((size_t)b << 22);   // b * H*W*C

    // ---- h = relu(conv3x3(x, w3) + b3), lane = input channel ----
    float h0 = 0.f, h1 = 0.f, h2 = 0.f, h3 = 0.f;
    float h4 = 0.f, h5 = 0.f, h6 = 0.f, h7 = 0.f;
#pragma unroll
    for (int dy = -1; dy <= 1; ++dy) {
        int yy = yq + dy;
        if ((unsigned)yy >= (unsigned)Hq) continue;
#pragma unroll
        for (int dx = -1; dx <= 1; ++dx) {
            int xx = xq + dx;
            if ((unsigned)xx >= (unsigned)Wq) continue;
            float xv = img[(size_t)(((yy << 8) + xx) << 6) + lane];
            const float* wp = w3 + (size_t)((((dy + 1) * 3 + dx + 1) << 6) + lane) * HID;
            float4 wv0 = *(const float4*)(wp);
            float4 wv1 = *(const float4*)(wp + 4);
            h0 = fmaf(xv, wv0.x, h0);
            h1 = fmaf(xv, wv0.y, h1);
            h2 = fmaf(xv, wv0.z, h2);
            h3 = fmaf(xv, wv0.w, h3);
            h4 = fmaf(xv, wv1.x, h4);
            h5 = fmaf(xv, wv1.y, h5);
            h6 = fmaf(xv, wv1.z, h6);
            h7 = fmaf(xv, wv1.w, h7);
        }
    }
    const int j = lane & 7;
    float hsum = fold8(h0, h1, h2, h3, h4, h5, h6, h7, lane);
    float h_l = fmaxf(hsum + b3[j], 0.f);

    // ---- theta = pi * sigmoid(w1 . h + b1) ----
    float zp = h_l * w1[j];
    zp += __shfl_xor(zp, 1, 64);
    zp += __shfl_xor(zp, 2, 64);
    zp += __shfl_xor(zp, 4, 64);
    float z = zp + b1[0];
    float theta = PI_F * __builtin_amdgcn_rcpf(1.f + __expf(-z));
    float ct = __cosf(theta);
    float st = __sinf(theta);

    // ---- oriented pooling (tangential & normal) ----
    const float fy = (float)yq, fx = (float)xq;
    float acc_t = 0.f, acc_n = 0.f;
#pragma unroll
    for (int t = -4; t <= 4; ++t) {
        float tf = (float)t;
        acc_t += bilin_s(img, fmaf(tf, st, fy), fmaf(tf, ct, fx), lane);
        acc_n += bilin_s(img, fmaf(tf, ct, fy), fmaf(-tf, st, fx), lane);
    }
    float tanv = acc_t * (1.f / 9.f);
    float norv = acc_n * (1.f / 9.f);

    // ---- r = relu(wr . [tan;nor] + br) ----
    const float* wrp0 = wr + (size_t)lane * HID;
    const float* wrp1 = wr + (size_t)(64 + lane) * HID;
    float4 a0 = *(const float4*)(wrp0);
    float4 a1 = *(const float4*)(wrp0 + 4);
    float4 c0 = *(const float4*)(wrp1);
    float4 c1 = *(const float4*)(wrp1 + 4);
    float p0 = fmaf(tanv, a0.x, norv * c0.x);
    float p1 = fmaf(tanv, a0.y, norv * c0.y);
    float p2 = fmaf(tanv, a0.z, norv * c0.z);
    float p3 = fmaf(tanv, a0.w, norv * c0.w);
    float p4 = fmaf(tanv, a1.x, norv * c1.x);
    float p5 = fmaf(tanv, a1.y, norv * c1.y);
    float p6 = fmaf(tanv, a1.z, norv * c1.z);
    float p7 = fmaf(tanv, a1.w, norv * c1.w);
    float rsum = fold8(p0, p1, p2, p3, p4, p5, p6, p7, lane);
    float r_l = fmaxf(rsum + br[j], 0.f);   // lane holds r[j], j = lane&7

    // broadcast: slot m holds r[j ^ m]
    float rb0 = r_l;
    float rb1 = __shfl_xor(rb0, 1, 64);
    float rb2 = __shfl_xor(rb0, 2, 64);
    float rb3 = __shfl_xor(rb1, 2, 64);
    float rb4 = __shfl_xor(rb0, 4, 64);
    float rb5 = __shfl_xor(rb1, 4, 64);
    float rb6 = __shfl_xor(rb2, 4, 64);
    float rb7 = __shfl_xor(rb3, 4, 64);

    // ---- w = sigmoid(we . r + be); out = (w_tan + w_nor) * x ----
    // row for slot m is (j^m); (j^m)*128 floats = base ^ (m<<7) in float units
    const float* web = we + ((size_t)j << 7) + lane;   // row j, column lane
    float zt = be[lane];
    float zn = be[64 + lane];
    zt = fmaf(rb0, web[0],            zt); zn = fmaf(rb0, web[64],            zn);
    zt = fmaf(rb1, *(const float*)((uintptr_t)web ^ (1u << 9)),        zt);
    zn = fmaf(rb1, *(const float*)(((uintptr_t)web ^ (1u << 9)) + 256), zn);
    zt = fmaf(rb2, *(const float*)((uintptr_t)web ^ (2u << 9)),        zt);
    zn = fmaf(rb2, *(const float*)(((uintptr_t)web ^ (2u << 9)) + 256), zn);
    zt = fmaf(rb3, *(const float*)((uintptr_t)web ^ (3u << 9)),        zt);
    zn = fmaf(rb3, *(const float*)(((uintptr_t)web ^ (3u << 9)) + 256), zn);
    zt = fmaf(rb4, *(const float*)((uintptr_t)web ^ (4u << 9)),        zt);
    zn = fmaf(rb4, *(const float*)(((uintptr_t)web ^ (4u << 9)) + 256), zn);
    zt = fmaf(rb5, *(const float*)((uintptr_t)web ^ (5u << 9)),        zt);
    zn = fmaf(rb5, *(const float*)(((uintptr_t)web ^ (5u << 9)) + 256), zn);
    zt = fmaf(rb6, *(const float*)((uintptr_t)web ^ (6u << 9)),        zt);
    zn = fmaf(rb6, *(const float*)(((uintptr_t)web ^ (6u << 9)) + 256), zn);
    zt = fmaf(rb7, *(const float*)((uintptr_t)web ^ (7u << 9)),        zt);
    zn = fmaf(rb7, *(const float*)(((uintptr_t)web ^ (7u << 9)) + 256), zn);

    float wt = __builtin_amdgcn_rcpf(1.f + __expf(-zt));
    float wn = __builtin_amdgcn_rcpf(1.f + __expf(-zn));
    float xc = img[(size_t)(((yq << 8) + xq) << 6) + lane];
    out[((size_t)wid << 6) + lane] = (wt + wn) * xc;
}

extern "C" void kernel_launch(void* const* d_in, const int* in_sizes, int n_in,
                              void* d_out, int out_size, void* d_ws, size_t ws_size,
                              hipStream_t stream) {
    const float* x  = (const float*)d_in[0];
    const float* w3 = (const float*)d_in[1];
    const float* b3 = (const float*)d_in[2];
    const float* w1 = (const float*)d_in[3];
    const float* b1 = (const float*)d_in[4];
    const float* wr = (const float*)d_in[5];
    const float* br = (const float*)d_in[6];
    const float* we = (const float*)d_in[7];
    const float* be = (const float*)d_in[8];
    float* out = (float*)d_out;

    const int total_waves = Bq * Hq * Wq;   // one wave per pixel
    dim3 grid(total_waves / 4), block(256); // 4 waves per block
    oca_kernel<<<grid, block, 0, stream>>>(x, w3, b3, w1, b1, wr, br, we, be, out);
}